// Round 5
// baseline (169.479 us; speedup 1.0000x reference)
//
#include <hip/hip_runtime.h>
#include <stdint.h>

// CausalSelfAttention: B=128 T=256 C=384 H=6 hd=64
// Pipeline: cvt(f32->bf16) -> GEMM1 qkv(+bias, bf16) -> fused causal attention -> GEMM2 proj(+bias, f32)
// All matmuls via v_mfma_f32_16x16x32_bf16 (f32 accum). Harness tolerance is bf16-floor (9.3e-2).

typedef unsigned short u16;
typedef __attribute__((ext_vector_type(8))) short short8;   // 8 bf16 (A/B frag)
typedef __attribute__((ext_vector_type(4))) short short4v;  // 4 bf16 (half frag)
typedef __attribute__((ext_vector_type(4))) float float4v;  // C/D frag

__device__ __forceinline__ u16 f2b(float f){            // f32 -> bf16 RNE
  union { float f; uint32_t u; } cv; cv.f = f;
  uint32_t u = cv.u;
  u += 0x7FFFu + ((u >> 16) & 1u);
  return (u16)(u >> 16);
}

__device__ __forceinline__ float4v mfma16(short8 a, short8 b, float4v c){
  return __builtin_amdgcn_mfma_f32_16x16x32_bf16(a, b, c, 0, 0, 0);
}

// async global->LDS, 16B per lane. LDS dest = wave-uniform base + lane*16 (HW rule).
__device__ __forceinline__ void gld16(const void* g, void* l){
  __builtin_amdgcn_global_load_lds((__attribute__((address_space(1))) const void*)g,
                                   (__attribute__((address_space(3))) void*)l, 16, 0, 0);
}

// ---------------------------------------------------------------------------
// Kernel 1: f32 -> bf16 conversion for x, w_attn, w_proj (float4 -> 4x bf16)
// ---------------------------------------------------------------------------
__global__ __launch_bounds__(256) void cvt3(
    const float* __restrict__ a, u16* __restrict__ da, int na,
    const float* __restrict__ b, u16* __restrict__ db, int nb,
    const float* __restrict__ c, u16* __restrict__ dc, int nc)
{
  const int total = na + nb + nc;  // counts in float4 units
  for (int i = blockIdx.x * blockDim.x + threadIdx.x; i < total;
       i += gridDim.x * blockDim.x){
    const float* s; u16* d; int j = i;
    if (j < na)           { s = a; d = da; }
    else if (j < na + nb) { j -= na; s = b; d = db; }
    else                  { j -= na + nb; s = c; d = dc; }
    const float4 v = ((const float4*)s)[j];
    ushort4 o;
    o.x = f2b(v.x); o.y = f2b(v.y); o.z = f2b(v.z); o.w = f2b(v.w);
    ((ushort4*)d)[j] = o;
  }
}

// ---------------------------------------------------------------------------
// Kernel 2/4: bf16 GEMM  C[M,N] = A[M,K] * B[N,K]^T + bias  (nn.Linear layout)
// Block tile 256x128, BK=32, 4 waves; WAVE TILE 64x128 (FLOP/LDS-byte = 42.7,
// vs 32 for 64x64 -- MFMA now dominates the LDS port: 621 vs ~450 cyc/CU/step).
// Inner loop: load one B-frag, feed 4 MFMAs -> 12 ds_read : 32 MFMA per wave.
// T3 minimal 2-phase: double-buffered LDS; STAGE(kt+1) issued BEFORE compute
// of kt; ONE __syncthreads per K-step. XOR swizzle keeps reads conflict-free.
// Grid: 1-D XCD-chunked: xcd=id&7 owns 16 xt (A-set 3MB < 4MB L2) x all yt.
// ---------------------------------------------------------------------------
template<bool OUT_BF16>
__global__ __launch_bounds__(256) void gemm_k(
    const u16* __restrict__ A, const u16* __restrict__ B,
    const float* __restrict__ bias, void* __restrict__ Cout,
    const int M, const int N, const int K)
{
  __shared__ u16 Alds[2][256*32];
  __shared__ u16 Blds[2][128*32];
  const int tid  = threadIdx.x;
  const int lane = tid & 63;
  const int wave = tid >> 6;
  const int lrow = lane & 15;
  const int g    = lane >> 4;

  // XCD-chunked decode: requires M/256 == 128 (16 xt per XCD)
  const int id    = blockIdx.x;
  const int local = id >> 3;
  const int xt = (id & 7) * 16 + (local & 15);
  const int yt = local >> 4;
  const int tm = xt * 256;
  const int tn = yt * 128;
  const int wm = wave * 64;          // wave owns rows [wm, wm+64), all 128 cols

  float4v acc[4][8];
  #pragma unroll
  for (int i = 0; i < 4; ++i)
    #pragma unroll
    for (int j = 0; j < 8; ++j) acc[i][j] = (float4v){0.f, 0.f, 0.f, 0.f};

  // staging geometry: chunk c (1KB) = 16 rows x 32 cols; src granule pre-swizzled
  const int srow = lane >> 2;                               // row within chunk
  const int sg   = ((lane & 3) ^ ((lane >> 3) & 3)) << 3;   // swizzled src granule (elems)
  const int key  = (lrow >> 1) & 3;                         // read-side swizzle key

  auto STAGE = [&](int kt, int buf){
    #pragma unroll
    for (int j = 0; j < 4; ++j){                 // A: 16 chunks, 4 per wave
      const int c = wave * 4 + j;
      const int row = c * 16 + srow;
      gld16(A + (size_t)(tm + row) * K + kt * 32 + sg, &Alds[buf][c * 512]);
    }
    #pragma unroll
    for (int j = 0; j < 2; ++j){                 // B: 8 chunks, 2 per wave
      const int c = wave * 2 + j;
      const int row = c * 16 + srow;
      gld16(B + (size_t)(tn + row) * K + kt * 32 + sg, &Blds[buf][c * 512]);
    }
  };

  const int nkt = K >> 5;
  STAGE(0, 0);
  __syncthreads();                       // buf0 ready
  for (int kt = 0; kt < nkt; ++kt){
    const int buf = kt & 1;
    if (kt + 1 < nkt) STAGE(kt + 1, buf ^ 1);   // in flight during compute
    short8 af[4];
    #pragma unroll
    for (int i = 0; i < 4; ++i)
      af[i] = *(const short8*)&Alds[buf][(wm + i * 16 + lrow) * 32 + ((g ^ key) << 3)];
    #pragma unroll
    for (int ni = 0; ni < 8; ++ni){
      const short8 bf = *(const short8*)&Blds[buf][(ni * 16 + lrow) * 32 + ((g ^ key) << 3)];
      #pragma unroll
      for (int mi = 0; mi < 4; ++mi)
        acc[mi][ni] = mfma16(af[mi], bf, acc[mi][ni]);
    }
    __syncthreads();                     // stage(kt+1) landed + buf reads done
  }

  // epilogue: D layout col=lane&15, row=(lane>>4)*4+reg (HW-verified)
  #pragma unroll
  for (int mi = 0; mi < 4; ++mi){
    #pragma unroll
    for (int ni = 0; ni < 8; ++ni){
      const int gcol = tn + ni * 16 + lrow;
      const float bs = bias[gcol];
      #pragma unroll
      for (int r = 0; r < 4; ++r){
        const int grow = tm + wm + mi * 16 + g * 4 + r;
        const float v = acc[mi][ni][r] + bs;
        if (OUT_BF16) ((u16*)Cout)[(size_t)grow * N + gcol] = f2b(v);
        else          ((float*)Cout)[(size_t)grow * N + gcol] = v;
      }
    }
  }
}

// ---------------------------------------------------------------------------
// Kernel 3: fused causal attention, one workgroup per (b,h), 4 waves.
// Swapped QK^T (S^T = K*Q^T) so softmax is lane-local(+2 shfl) and P feeds PV
// directly from registers. K in LDS with XOR row swizzle. V stored TRANSPOSED
// in LDS (Vt[d][t], 4-elem granules XOR-swizzled by d&15) so the PV B-operand
// is two plain ds_read_b64 with the SAME (g,i)->t slot map as the P fragment.
// ---------------------------------------------------------------------------
__global__ __launch_bounds__(256) void attn_k(
    const u16* __restrict__ qkv, u16* __restrict__ y)
{
  __shared__ u16 Klds[256 * 64];   // K rows, 16B chunks xor-swizzled within row
  __shared__ u16 Vt[64 * 256];     // V^T: row d (0..63), 256 t; granule p(4 t) at p^(d&15)
  const int tid  = threadIdx.x;
  const int lane = tid & 63;
  const int wave = tid >> 6;
  const int lrow = lane & 15;
  const int g    = lane >> 4;
  const int bh = blockIdx.x;
  const int b = bh / 6, h = bh % 6;
  const u16* qb = qkv + (size_t)b * 256 * 1152 + h * 64;
  const u16* kb = qb + 384;
  const u16* vb = qb + 768;

  // ---- stage K: elem K[r][c16*8+e] -> Klds[r*64 + (c16^(r&7))*8 + e]
  #pragma unroll
  for (int j = 0; j < 8; ++j){
    const int c = wave * 8 + j;                 // 1KB chunk = 8 K-rows
    const int row = c * 8 + (lane >> 3);
    const int col = (((lane & 7) ^ (lane >> 3)) << 3);
    gld16(kb + (size_t)row * 1152 + col, &Klds[c * 512]);
  }
  // ---- stage V^T: lane owns column d=lane, wave owns t-quarter.
  {
    const int d  = lane;
    const int t0 = wave * 64;
    const int sv = d & 15;
    #pragma unroll
    for (int c4 = 0; c4 < 16; ++c4){
      const size_t base = (size_t)(t0 + c4 * 4) * 1152 + d;
      const u16 e0 = vb[base];
      const u16 e1 = vb[base + 1152];
      const u16 e2 = vb[base + 2304];
      const u16 e3 = vb[base + 3456];
      short4v g4; g4[0] = (short)e0; g4[1] = (short)e1; g4[2] = (short)e2; g4[3] = (short)e3;
      const int pos = (t0 >> 2) + (c4 ^ sv);    // source granule p = t0/4+c4 at p^sv
      *(short4v*)&Vt[(size_t)d * 256 + (pos << 2)] = g4;
    }
  }
  __syncthreads();

  for (int it = 0; it < 4; ++it){
    const int rb = wave + it * 4;    // q-row tile index 0..15
    const int q0 = rb * 16;
    const u16* qrow = qb + (size_t)(q0 + lrow) * 1152 + g * 8;
    const short8 qf0 = *(const short8*)(qrow);
    const short8 qf1 = *(const short8*)(qrow + 32);

    // S^T[t][q]: lane holds t = nt*16 + g*4 + r for its q = q0 + lrow
    float4v s[16];
    #pragma unroll
    for (int nt = 0; nt < 16; ++nt){
      if (nt <= rb){                       // causal: tiles fully above diagonal skipped
        const int row = nt * 16 + lrow;    // K row (A operand m = lane&15)
        const int swk = lrow & 7;
        const short8 k0 = *(const short8*)&Klds[row * 64 + ((g ^ swk) << 3)];
        const short8 k1 = *(const short8*)&Klds[row * 64 + (((4 + g) ^ swk) << 3)];
        float4v a = (float4v){0.f, 0.f, 0.f, 0.f};
        a = mfma16(k0, qf0, a);
        a = mfma16(k1, qf1, a);
        if (nt == rb){                     // diagonal tile mask: t > q
          #pragma unroll
          for (int r = 0; r < 4; ++r)
            a[r] = (g * 4 + r > lrow) ? -1e30f : a[r];
        }
        s[nt] = a;
      }
    }

    // softmax over t for fixed q: lane-local + reduce across the 4 lane-groups
    float mx = -1e30f;
    #pragma unroll
    for (int nt = 0; nt < 16; ++nt) if (nt <= rb){
      #pragma unroll
      for (int r = 0; r < 4; ++r) mx = fmaxf(mx, s[nt][r]);
    }
    mx = fmaxf(mx, __shfl_xor(mx, 16));
    mx = fmaxf(mx, __shfl_xor(mx, 32));
    float sum = 0.f;
    #pragma unroll
    for (int nt = 0; nt < 16; ++nt) if (nt <= rb){
      #pragma unroll
      for (int r = 0; r < 4; ++r){
        // scale 1/sqrt(64)=0.125 folded: exp2((s-m)*0.125*log2e)
        const float p = exp2f((s[nt][r] - mx) * 0.18033688011112042f);
        s[nt][r] = p;
        sum += p;
      }
    }
    sum += __shfl_xor(sum, 16);
    sum += __shfl_xor(sum, 32);
    const float rs = 1.f / sum;
    #pragma unroll
    for (int nt = 0; nt < 16; ++nt) if (nt <= rb) s[nt] *= rs;

    // PV: O[q][d] += P[q][t] V[t][d]; P is the A operand straight from regs.
    // slot map (BOTH operands): i<4 -> t=kt*32+g*4+i ; i>=4 -> t=kt*32+16+g*4+(i-4)
    float4v o0 = (float4v){0,0,0,0}, o1 = (float4v){0,0,0,0};
    float4v o2 = (float4v){0,0,0,0}, o3 = (float4v){0,0,0,0};
    const int svr = lrow;                      // read-row swizzle: (dt*16+lrow)&15
    #pragma unroll
    for (int kt = 0; kt < 8; ++kt){
      if (2 * kt <= rb){
        short8 pa;
        #pragma unroll
        for (int r = 0; r < 4; ++r) pa[r] = (short)f2b(s[2 * kt][r]);
        if (2 * kt + 1 <= rb){
          #pragma unroll
          for (int r = 0; r < 4; ++r) pa[4 + r] = (short)f2b(s[2 * kt + 1][r]);
        } else {
          #pragma unroll
          for (int r = 0; r < 4; ++r) pa[4 + r] = 0;
        }
        const int plo = ((kt * 8 + g) ^ svr) << 2;       // granule t=kt*32+g*4..+3
        const int phi = ((kt * 8 + 4 + g) ^ svr) << 2;   // granule t=kt*32+16+g*4..+3
        #pragma unroll
        for (int dt = 0; dt < 4; ++dt){
          const u16* vrow = &Vt[(size_t)(dt * 16 + lrow) * 256];
          const short4v vlo = *(const short4v*)&vrow[plo];
          const short4v vhi = *(const short4v*)&vrow[phi];
          const short8 bf = __builtin_shufflevector(vlo, vhi, 0,1,2,3,4,5,6,7);
          if      (dt == 0) o0 = mfma16(pa, bf, o0);
          else if (dt == 1) o1 = mfma16(pa, bf, o1);
          else if (dt == 2) o2 = mfma16(pa, bf, o2);
          else              o3 = mfma16(pa, bf, o3);
        }
      }
    }

    // write O: D row=(g*4+r) -> q-within-tile, col=lrow -> d within 16-tile
    u16* yb = y + (size_t)(b * 256 + q0) * 384 + h * 64;
    #pragma unroll
    for (int r = 0; r < 4; ++r){
      const int q = g * 4 + r;
      yb[(size_t)q * 384 +  0 + lrow] = f2b(o0[r]);
      yb[(size_t)q * 384 + 16 + lrow] = f2b(o1[r]);
      yb[(size_t)q * 384 + 32 + lrow] = f2b(o2[r]);
      yb[(size_t)q * 384 + 48 + lrow] = f2b(o3[r]);
    }
  }
}

// ---------------------------------------------------------------------------
extern "C" void kernel_launch(void* const* d_in, const int* in_sizes, int n_in,
                              void* d_out, int out_size, void* d_ws, size_t ws_size,
                              hipStream_t stream)
{
  const float* x      = (const float*)d_in[0];
  const float* w_attn = (const float*)d_in[1];
  const float* b_attn = (const float*)d_in[2];
  const float* w_proj = (const float*)d_in[3];
  const float* b_proj = (const float*)d_in[4];
  float* out = (float*)d_out;

  // workspace layout (bytes, 256-aligned)
  char* ws = (char*)d_ws;
  u16* xb  = (u16*)(ws);                 // 25,165,824  x as bf16 [32768,384]
  u16* wab = (u16*)(ws + 25165824);      //    884,736  w_attn bf16 [1152,384]
  u16* wpb = (u16*)(ws + 26050560);      //    294,912  w_proj bf16 [384,384]
  u16* qkv = (u16*)(ws + 26345472);      // 75,497,472  qkv bf16 [32768,1152]
  u16* yb  = (u16*)(ws + 101842944);     // 25,165,824  attn out bf16 [32768,384]
  if (ws_size < 127008768) return;       // insufficient scratch -> fail loudly

  cvt3<<<2048, 256, 0, stream>>>(x, xb, 3145728,          // 12.58M/4
                                 w_attn, wab, 110592,     // 442368/4
                                 w_proj, wpb, 36864);     // 147456/4
  // grids: 1-D XCD-chunked; M-tiles(256-row)=128, N-tiles(128-col)=9 / 3
  gemm_k<true ><<<1152, 256, 0, stream>>>(xb, wab, b_attn, qkv, 32768, 1152, 384);
  attn_k<<<768, 256, 0, stream>>>(qkv, yb);
  gemm_k<false><<<384, 256, 0, stream>>>(yb, wpb, b_proj, out, 32768, 384, 384);
}

// Round 6
// 122.700 us; speedup vs baseline: 1.3813x; 1.3813x over previous
//
#include <hip/hip_runtime.h>
#include <stdint.h>

// CausalSelfAttention: B=128 T=256 C=384 H=6 hd=64
// Pipeline: cvt(f32->bf16) -> GEMM1 qkv(+bias, bf16) -> fused causal attention -> GEMM2 proj(+bias, f32)
// All matmuls via v_mfma_f32_16x16x32_bf16 (f32 accum). Harness tolerance is bf16-floor (9.3e-2).

typedef unsigned short u16;
typedef __attribute__((ext_vector_type(8))) short short8;   // 8 bf16 (A/B frag)
typedef __attribute__((ext_vector_type(4))) short short4v;  // 4 bf16 (half frag)
typedef __attribute__((ext_vector_type(4))) float float4v;  // C/D frag

__device__ __forceinline__ u16 f2b(float f){            // f32 -> bf16 RNE
  union { float f; uint32_t u; } cv; cv.f = f;
  uint32_t u = cv.u;
  u += 0x7FFFu + ((u >> 16) & 1u);
  return (u16)(u >> 16);
}

__device__ __forceinline__ float4v mfma16(short8 a, short8 b, float4v c){
  return __builtin_amdgcn_mfma_f32_16x16x32_bf16(a, b, c, 0, 0, 0);
}

// async global->LDS, 16B per lane. LDS dest = wave-uniform base + lane*16 (HW rule).
__device__ __forceinline__ void gld16(const void* g, void* l){
  __builtin_amdgcn_global_load_lds((__attribute__((address_space(1))) const void*)g,
                                   (__attribute__((address_space(3))) void*)l, 16, 0, 0);
}

// ---------------------------------------------------------------------------
// Kernel 1: f32 -> bf16 conversion for x, w_attn, w_proj (float4 -> 4x bf16)
// ---------------------------------------------------------------------------
__global__ __launch_bounds__(256) void cvt3(
    const float* __restrict__ a, u16* __restrict__ da, int na,
    const float* __restrict__ b, u16* __restrict__ db, int nb,
    const float* __restrict__ c, u16* __restrict__ dc, int nc)
{
  const int total = na + nb + nc;  // counts in float4 units
  for (int i = blockIdx.x * blockDim.x + threadIdx.x; i < total;
       i += gridDim.x * blockDim.x){
    const float* s; u16* d; int j = i;
    if (j < na)           { s = a; d = da; }
    else if (j < na + nb) { j -= na; s = b; d = db; }
    else                  { j -= na + nb; s = c; d = dc; }
    const float4 v = ((const float4*)s)[j];
    ushort4 o;
    o.x = f2b(v.x); o.y = f2b(v.y); o.z = f2b(v.z); o.w = f2b(v.w);
    ((ushort4*)d)[j] = o;
  }
}

// ---------------------------------------------------------------------------
// Kernel 2/4: bf16 GEMM  C[M,N] = A[M,K] * B[N,K]^T + bias  (nn.Linear layout)
// Block tile 256x128, BK=32, 4 waves, wave tile 64x128.
// T4 counted-vmcnt pipeline, 3 LDS buffers, RAW s_barrier (no vmcnt-0 drain
// in the main loop -- the __syncthreads drain was the R4/R5 ~550TF ceiling):
//   per tile t:  vmcnt(6)->B1 ; 12x ds_read ; lgkmcnt(0)->B2 ; STAGE(t+2) ; MFMA
// Race audit: STAGE(t+2) overwrites buf[(t+2)%3]=buf[(t-1)%3], whose readers
// finished (lgkmcnt(0)) before B2(t-1) < B2(t) <= STAGE(t+2). Loads for tile
// t+1 (6, in flight) target buf[(t+1)%3], disjoint from read-buf and stage-buf.
// vmcnt(6) at B1(t): outstanding = tile t's 6 + tile t+1's 6; waiting to <=6
// retires (FIFO) exactly tile t's own -- barrier then makes all waves' writes
// visible. Last tile waits vmcnt(0) (nothing newer in flight).
// Grid: 1-D XCD-chunked, yt-fastest (A-panel read once; B stays hot in L2).
// ---------------------------------------------------------------------------
template<bool OUT_BF16>
__global__ __launch_bounds__(256, 2) void gemm_k(
    const u16* __restrict__ A, const u16* __restrict__ B,
    const float* __restrict__ bias, void* __restrict__ Cout,
    const int M, const int N, const int K)
{
  __shared__ u16 Alds[3][256*32];   // 3 x 16KB
  __shared__ u16 Blds[3][128*32];   // 3 x  8KB  -> 72KB total, 2 blocks/CU
  const int tid  = threadIdx.x;
  const int lane = tid & 63;
  const int wave = tid >> 6;
  const int lrow = lane & 15;
  const int g    = lane >> 4;

  // XCD-chunked decode, yt-fastest. Requires M == 256*128.
  const int NYT   = N >> 7;
  const int id    = blockIdx.x;
  const int local = id >> 3;
  const int xtl   = local / NYT;
  const int yt    = local - xtl * NYT;
  const int xt    = (id & 7) * 16 + xtl;
  const int tm = xt * 256;
  const int tn = yt * 128;
  const int wm = wave * 64;          // wave owns rows [wm,wm+64) x all 128 cols

  float4v acc[4][8];
  #pragma unroll
  for (int i = 0; i < 4; ++i)
    #pragma unroll
    for (int j = 0; j < 8; ++j) acc[i][j] = (float4v){0.f, 0.f, 0.f, 0.f};

  // staging geometry: chunk c (1KB) = 16 rows x 32 cols; src granule pre-swizzled
  const int srow = lane >> 2;                               // row within chunk
  const int sg   = ((lane & 3) ^ ((lane >> 3) & 3)) << 3;   // swizzled src granule (elems)
  const int key  = (lrow >> 1) & 3;                         // read-side swizzle key

  auto STAGE = [&](int kt, int buf){                        // 6 loads/thread
    #pragma unroll
    for (int j = 0; j < 4; ++j){                 // A: 16 chunks, 4 per wave
      const int c = wave * 4 + j;
      const int row = c * 16 + srow;
      gld16(A + (size_t)(tm + row) * K + kt * 32 + sg, &Alds[buf][c * 512]);
    }
    #pragma unroll
    for (int j = 0; j < 2; ++j){                 // B: 8 chunks, 2 per wave
      const int c = wave * 2 + j;
      const int row = c * 16 + srow;
      gld16(B + (size_t)(tn + row) * K + kt * 32 + sg, &Blds[buf][c * 512]);
    }
  };

  const int nkt = K >> 5;            // 12
  STAGE(0, 0);
  STAGE(1, 1);
  int b0 = 0;                        // buf of current tile (kt % 3)
  for (int kt = 0; kt < nkt; ++kt){
    // B1: own loads for tile kt retired (FIFO), tile kt+1's may stay in flight
    if (kt + 1 < nkt) asm volatile("s_waitcnt vmcnt(6)" ::: "memory");
    else              asm volatile("s_waitcnt vmcnt(0)" ::: "memory");
    __builtin_amdgcn_s_barrier();

    short8 af[4], bf[8];
    #pragma unroll
    for (int i = 0; i < 4; ++i)
      af[i] = *(const short8*)&Alds[b0][(wm + i * 16 + lrow) * 32 + ((g ^ key) << 3)];
    #pragma unroll
    for (int ni = 0; ni < 8; ++ni)
      bf[ni] = *(const short8*)&Blds[b0][(ni * 16 + lrow) * 32 + ((g ^ key) << 3)];

    // B2: my reads are complete -> safe for any wave to overwrite oldest buffer
    asm volatile("s_waitcnt lgkmcnt(0)" ::: "memory");
    __builtin_amdgcn_sched_barrier(0);
    __builtin_amdgcn_s_barrier();

    const int bs = (b0 == 0) ? 2 : b0 - 1;       // (kt+2) % 3
    if (kt + 2 < nkt) STAGE(kt + 2, bs);

    __builtin_amdgcn_s_setprio(1);
    #pragma unroll
    for (int ni = 0; ni < 8; ++ni)
      #pragma unroll
      for (int mi = 0; mi < 4; ++mi)
        acc[mi][ni] = mfma16(af[mi], bf[ni], acc[mi][ni]);
    __builtin_amdgcn_s_setprio(0);

    b0 = (b0 == 2) ? 0 : b0 + 1;
  }

  // epilogue: D layout col=lane&15, row=(lane>>4)*4+reg (HW-verified)
  #pragma unroll
  for (int mi = 0; mi < 4; ++mi){
    #pragma unroll
    for (int ni = 0; ni < 8; ++ni){
      const int gcol = tn + ni * 16 + lrow;
      const float bs = bias[gcol];
      #pragma unroll
      for (int r = 0; r < 4; ++r){
        const int grow = tm + wm + mi * 16 + g * 4 + r;
        const float v = acc[mi][ni][r] + bs;
        if (OUT_BF16) ((u16*)Cout)[(size_t)grow * N + gcol] = f2b(v);
        else          ((float*)Cout)[(size_t)grow * N + gcol] = v;
      }
    }
  }
}

// ---------------------------------------------------------------------------
// Kernel 3: fused causal attention, one workgroup per (b,h), 4 waves.
// Swapped QK^T (S^T = K*Q^T) so softmax is lane-local(+2 shfl) and P feeds PV
// directly from registers. K in LDS with XOR row swizzle. V stored TRANSPOSED
// in LDS (Vt[d][t], 4-elem granules XOR-swizzled by d&15) so the PV B-operand
// is two plain ds_read_b64 with the SAME (g,i)->t slot map as the P fragment.
// ---------------------------------------------------------------------------
__global__ __launch_bounds__(256) void attn_k(
    const u16* __restrict__ qkv, u16* __restrict__ y)
{
  __shared__ u16 Klds[256 * 64];   // K rows, 16B chunks xor-swizzled within row
  __shared__ u16 Vt[64 * 256];     // V^T: row d (0..63), 256 t; granule p(4 t) at p^(d&15)
  const int tid  = threadIdx.x;
  const int lane = tid & 63;
  const int wave = tid >> 6;
  const int lrow = lane & 15;
  const int g    = lane >> 4;
  const int bh = blockIdx.x;
  const int b = bh / 6, h = bh % 6;
  const u16* qb = qkv + (size_t)b * 256 * 1152 + h * 64;
  const u16* kb = qb + 384;
  const u16* vb = qb + 768;

  // ---- stage K: elem K[r][c16*8+e] -> Klds[r*64 + (c16^(r&7))*8 + e]
  #pragma unroll
  for (int j = 0; j < 8; ++j){
    const int c = wave * 8 + j;                 // 1KB chunk = 8 K-rows
    const int row = c * 8 + (lane >> 3);
    const int col = (((lane & 7) ^ (lane >> 3)) << 3);
    gld16(kb + (size_t)row * 1152 + col, &Klds[c * 512]);
  }
  // ---- stage V^T: lane owns column d=lane, wave owns t-quarter.
  {
    const int d  = lane;
    const int t0 = wave * 64;
    const int sv = d & 15;
    #pragma unroll
    for (int c4 = 0; c4 < 16; ++c4){
      const size_t base = (size_t)(t0 + c4 * 4) * 1152 + d;
      const u16 e0 = vb[base];
      const u16 e1 = vb[base + 1152];
      const u16 e2 = vb[base + 2304];
      const u16 e3 = vb[base + 3456];
      short4v g4; g4[0] = (short)e0; g4[1] = (short)e1; g4[2] = (short)e2; g4[3] = (short)e3;
      const int pos = (t0 >> 2) + (c4 ^ sv);    // source granule p = t0/4+c4 at p^sv
      *(short4v*)&Vt[(size_t)d * 256 + (pos << 2)] = g4;
    }
  }
  __syncthreads();

  for (int it = 0; it < 4; ++it){
    const int rb = wave + it * 4;    // q-row tile index 0..15
    const int q0 = rb * 16;
    const u16* qrow = qb + (size_t)(q0 + lrow) * 1152 + g * 8;
    const short8 qf0 = *(const short8*)(qrow);
    const short8 qf1 = *(const short8*)(qrow + 32);

    // S^T[t][q]: lane holds t = nt*16 + g*4 + r for its q = q0 + lrow
    float4v s[16];
    #pragma unroll
    for (int nt = 0; nt < 16; ++nt){
      if (nt <= rb){                       // causal: tiles fully above diagonal skipped
        const int row = nt * 16 + lrow;    // K row (A operand m = lane&15)
        const int swk = lrow & 7;
        const short8 k0 = *(const short8*)&Klds[row * 64 + ((g ^ swk) << 3)];
        const short8 k1 = *(const short8*)&Klds[row * 64 + (((4 + g) ^ swk) << 3)];
        float4v a = (float4v){0.f, 0.f, 0.f, 0.f};
        a = mfma16(k0, qf0, a);
        a = mfma16(k1, qf1, a);
        if (nt == rb){                     // diagonal tile mask: t > q
          #pragma unroll
          for (int r = 0; r < 4; ++r)
            a[r] = (g * 4 + r > lrow) ? -1e30f : a[r];
        }
        s[nt] = a;
      }
    }

    // softmax over t for fixed q: lane-local + reduce across the 4 lane-groups
    float mx = -1e30f;
    #pragma unroll
    for (int nt = 0; nt < 16; ++nt) if (nt <= rb){
      #pragma unroll
      for (int r = 0; r < 4; ++r) mx = fmaxf(mx, s[nt][r]);
    }
    mx = fmaxf(mx, __shfl_xor(mx, 16));
    mx = fmaxf(mx, __shfl_xor(mx, 32));
    float sum = 0.f;
    #pragma unroll
    for (int nt = 0; nt < 16; ++nt) if (nt <= rb){
      #pragma unroll
      for (int r = 0; r < 4; ++r){
        // scale 1/sqrt(64)=0.125 folded: exp2((s-m)*0.125*log2e)
        const float p = exp2f((s[nt][r] - mx) * 0.18033688011112042f);
        s[nt][r] = p;
        sum += p;
      }
    }
    sum += __shfl_xor(sum, 16);
    sum += __shfl_xor(sum, 32);
    const float rs = 1.f / sum;
    #pragma unroll
    for (int nt = 0; nt < 16; ++nt) if (nt <= rb) s[nt] *= rs;

    // PV: O[q][d] += P[q][t] V[t][d]; P is the A operand straight from regs.
    // slot map (BOTH operands): i<4 -> t=kt*32+g*4+i ; i>=4 -> t=kt*32+16+g*4+(i-4)
    float4v o0 = (float4v){0,0,0,0}, o1 = (float4v){0,0,0,0};
    float4v o2 = (float4v){0,0,0,0}, o3 = (float4v){0,0,0,0};
    const int svr = lrow;                      // read-row swizzle: (dt*16+lrow)&15
    #pragma unroll
    for (int kt = 0; kt < 8; ++kt){
      if (2 * kt <= rb){
        short8 pa;
        #pragma unroll
        for (int r = 0; r < 4; ++r) pa[r] = (short)f2b(s[2 * kt][r]);
        if (2 * kt + 1 <= rb){
          #pragma unroll
          for (int r = 0; r < 4; ++r) pa[4 + r] = (short)f2b(s[2 * kt + 1][r]);
        } else {
          #pragma unroll
          for (int r = 0; r < 4; ++r) pa[4 + r] = 0;
        }
        const int plo = ((kt * 8 + g) ^ svr) << 2;       // granule t=kt*32+g*4..+3
        const int phi = ((kt * 8 + 4 + g) ^ svr) << 2;   // granule t=kt*32+16+g*4..+3
        #pragma unroll
        for (int dt = 0; dt < 4; ++dt){
          const u16* vrow = &Vt[(size_t)(dt * 16 + lrow) * 256];
          const short4v vlo = *(const short4v*)&vrow[plo];
          const short4v vhi = *(const short4v*)&vrow[phi];
          const short8 bf = __builtin_shufflevector(vlo, vhi, 0,1,2,3,4,5,6,7);
          if      (dt == 0) o0 = mfma16(pa, bf, o0);
          else if (dt == 1) o1 = mfma16(pa, bf, o1);
          else if (dt == 2) o2 = mfma16(pa, bf, o2);
          else              o3 = mfma16(pa, bf, o3);
        }
      }
    }

    // write O: D row=(g*4+r) -> q-within-tile, col=lrow -> d within 16-tile
    u16* yb = y + (size_t)(b * 256 + q0) * 384 + h * 64;
    #pragma unroll
    for (int r = 0; r < 4; ++r){
      const int q = g * 4 + r;
      yb[(size_t)q * 384 +  0 + lrow] = f2b(o0[r]);
      yb[(size_t)q * 384 + 16 + lrow] = f2b(o1[r]);
      yb[(size_t)q * 384 + 32 + lrow] = f2b(o2[r]);
      yb[(size_t)q * 384 + 48 + lrow] = f2b(o3[r]);
    }
  }
}

// ---------------------------------------------------------------------------
extern "C" void kernel_launch(void* const* d_in, const int* in_sizes, int n_in,
                              void* d_out, int out_size, void* d_ws, size_t ws_size,
                              hipStream_t stream)
{
  const float* x      = (const float*)d_in[0];
  const float* w_attn = (const float*)d_in[1];
  const float* b_attn = (const float*)d_in[2];
  const float* w_proj = (const float*)d_in[3];
  const float* b_proj = (const float*)d_in[4];
  float* out = (float*)d_out;

  // workspace layout (bytes, 256-aligned)
  char* ws = (char*)d_ws;
  u16* xb  = (u16*)(ws);                 // 25,165,824  x as bf16 [32768,384]
  u16* wab = (u16*)(ws + 25165824);      //    884,736  w_attn bf16 [1152,384]
  u16* wpb = (u16*)(ws + 26050560);      //    294,912  w_proj bf16 [384,384]
  u16* qkv = (u16*)(ws + 26345472);      // 75,497,472  qkv bf16 [32768,1152]
  u16* yb  = (u16*)(ws + 101842944);     // 25,165,824  attn out bf16 [32768,384]
  if (ws_size < 127008768) return;       // insufficient scratch -> fail loudly

  cvt3<<<2048, 256, 0, stream>>>(x, xb, 3145728,          // 12.58M/4
                                 w_attn, wab, 110592,     // 442368/4
                                 w_proj, wpb, 36864);     // 147456/4
  // grids: 1-D XCD-chunked; M-tiles(256-row)=128 = 8 XCD x 16; N-tiles 9 / 3
  gemm_k<true ><<<1152, 256, 0, stream>>>(xb, wab, b_attn, qkv, 32768, 1152, 384);
  attn_k<<<768, 256, 0, stream>>>(qkv, yb);
  gemm_k<false><<<384, 256, 0, stream>>>(yb, wpb, b_proj, out, 32768, 384, 384);
}